// Round 6
// baseline (305.260 us; speedup 1.0000x reference)
//
#include <hip/hip_runtime.h>
#include <hip/hip_bf16.h>

#define BB 32
#define CC 64
#define HH 128
#define WW 128
#define OO 64
#define KK 4
#define HIDDEN 17
#define HW (HH*WW)

typedef __attribute__((ext_vector_type(8)))  short bf16x8;
typedef __attribute__((ext_vector_type(16))) float f32x16;

typedef __attribute__((address_space(3))) void       lds_void_t;
typedef const __attribute__((address_space(1))) void gbl_void_t;

__device__ __forceinline__ unsigned short f2bf(float f) {
    unsigned u = __float_as_uint(f);
    unsigned r = (u + 0x7FFFu + ((u >> 16) & 1u)) >> 16;   // RNE
    return (unsigned short)r;
}

// ---------------- zero pooled (must precede xpose_pool's atomics) ----------------
__global__ __launch_bounds__(256) void zero_pool_kernel(float* __restrict__ pooled) {
    int i = blockIdx.x * 256 + threadIdx.x;
    if (i < BB * CC) pooled[i] = 0.f;
}

// ---------------- Kernel 1 (fallback only): adaptive avg pool to [B,C] ----------------
__global__ __launch_bounds__(256) void pool_kernel(const float* __restrict__ x,
                                                   float* __restrict__ pooled) {
    int bc = blockIdx.x;              // b*64 + c
    const float* p = x + (size_t)bc * HW;
    float s = 0.f;
    for (int i = threadIdx.x; i < HW; i += 256) s += p[i];
    #pragma unroll
    for (int off = 32; off > 0; off >>= 1) s += __shfl_down(s, off, 64);
    __shared__ float warp_s[4];
    int lane = threadIdx.x & 63, wv = threadIdx.x >> 6;
    if (lane == 0) warp_s[wv] = s;
    __syncthreads();
    if (threadIdx.x == 0) {
        float t = warp_s[0] + warp_s[1] + warp_s[2] + warp_s[3];
        pooled[bc] = t * (1.f / (float)HW);
    }
}

// ---------------- Kernel 2 (fallback only): MLP -> softmax -> attn, agg_b ----------------
__global__ __launch_bounds__(256) void attn_kernel(const float* __restrict__ pooled,
                                                   const float* __restrict__ fc1_w,
                                                   const float* __restrict__ fc2_w,
                                                   const float* __restrict__ fc2_b,
                                                   const float* __restrict__ scale,
                                                   const float* __restrict__ bias,
                                                   float* __restrict__ attn,
                                                   float* __restrict__ agg_b) {
    __shared__ float s_attn[BB * KK];
    int tid = threadIdx.x;
    if (tid < BB) {
        int b = tid;
        const float* pb = pooled + b * CC;
        float h[HIDDEN];
        #pragma unroll
        for (int i = 0; i < HIDDEN; ++i) {
            float s = 0.f;
            for (int c = 0; c < CC; ++c) s += pb[c] * fc1_w[i * CC + c];
            h[i] = fmaxf(s, 0.f);
        }
        float sc = scale[0];
        float logits[KK];
        #pragma unroll
        for (int k = 0; k < KK; ++k) {
            float s = fc2_b[k];
            for (int j = 0; j < HIDDEN; ++j) s += h[j] * fc2_w[k * (HIDDEN + 2) + j];
            s += sc * fc2_w[k * (HIDDEN + 2) + HIDDEN];
            s += sc * fc2_w[k * (HIDDEN + 2) + HIDDEN + 1];
            logits[k] = s;
        }
        float m = fmaxf(fmaxf(logits[0], logits[1]), fmaxf(logits[2], logits[3]));
        float e[KK], tot = 0.f;
        #pragma unroll
        for (int k = 0; k < KK; ++k) { e[k] = __expf(logits[k] - m); tot += e[k]; }
        float inv = 1.f / tot;
        #pragma unroll
        for (int k = 0; k < KK; ++k) {
            float a = e[k] * inv;
            s_attn[b * KK + k] = a;
            attn[b * KK + k] = a;
        }
    }
    __syncthreads();
    for (int i = tid; i < BB * OO; i += blockDim.x) {
        int b = i >> 6;
        int o = i & 63;
        float s = 0.f;
        #pragma unroll
        for (int k = 0; k < KK; ++k) s += s_attn[b * KK + k] * bias[k * OO + o];
        agg_b[i] = s;
    }
}

// ---------------- Kernel 3a: fused MLP + weight-mix -> bf16 fragment layout ----------------
// grid (b4=8, otile=2, kc=4), 256 thr. Each block:
//   1. stages weight slice [4k][32 o][16 c][9 j] (73,728 B) into LDS, coalesced float4
//   2. computes attention for its 4 samples (redundantly; per-wave MLP, ~1 us)
//   3. emits wbf fragments (contiguous 1 KiB/wave writes); (otile==0,kc==0) blocks emit agg_b
// wbf layout: [b][j9][otile(2)][kc(4)][lane(64)][j2(4)] u32  == round-2 fragment layout
__global__ __launch_bounds__(256) void aggw_fused_kernel(const float* __restrict__ pooled,
                                                         const float* __restrict__ fc1_w,
                                                         const float* __restrict__ fc2_w,
                                                         const float* __restrict__ fc2_b,
                                                         const float* __restrict__ scale,
                                                         const float* __restrict__ bias,
                                                         const float* __restrict__ weight,
                                                         float* __restrict__ agg_b,
                                                         unsigned int* __restrict__ wbf) {
    __shared__ float4 sw4[128 * 37];     // 128 segs x (36 data + 1 pad) float4 = 75,776 B
    __shared__ float  sh[4][20];         // per-sample hidden
    __shared__ float  sa[4][4];          // per-sample attention
    const float* swf = (const float*)sw4;

    const int tid = threadIdx.x;
    const int b4  = blockIdx.x;          // 0..7
    const int oty = blockIdx.y;          // otile 0..1
    const int kcz = blockIdx.z;          // kc 0..3

    // ---- 1. stage weight slice: 4608 float4, 18 per thread, coalesced ----
    {
        const float4* w4 = (const float4*)weight;
        #pragma unroll
        for (int it = 0; it < 18; ++it) {
            int i   = tid + it * 256;
            int seg = i / 36;            // k*32 + o_local
            int off = i - seg * 36;
            int k   = seg >> 5;
            int o   = seg & 31;
            sw4[seg * 37 + off] = w4[(size_t)(k * 64 + oty * 32 + o) * 144 + kcz * 36 + off];
        }
    }
    // ---- 2. MLP for 4 samples (wave wv handles sample b4*4+wv) ----
    const int wv = tid >> 6, lane = tid & 63;
    const int bb = b4 * 4 + wv;
    if (lane < HIDDEN) {
        const float* pb = pooled + bb * CC;
        const float* f1 = fc1_w + lane * CC;
        float s = 0.f;
        #pragma unroll
        for (int c = 0; c < CC; ++c) s += pb[c] * f1[c];
        sh[wv][lane] = fmaxf(s, 0.f);
    }
    __syncthreads();
    if (lane == 0) {
        float sc = scale[0];
        float lg[KK];
        #pragma unroll
        for (int k = 0; k < KK; ++k) {
            float s = fc2_b[k];
            #pragma unroll
            for (int j = 0; j < HIDDEN; ++j) s += sh[wv][j] * fc2_w[k * (HIDDEN + 2) + j];
            s += sc * fc2_w[k * (HIDDEN + 2) + HIDDEN];
            s += sc * fc2_w[k * (HIDDEN + 2) + HIDDEN + 1];
            lg[k] = s;
        }
        float m = fmaxf(fmaxf(lg[0], lg[1]), fmaxf(lg[2], lg[3]));
        float e[KK], tot = 0.f;
        #pragma unroll
        for (int k = 0; k < KK; ++k) { e[k] = __expf(lg[k] - m); tot += e[k]; }
        float inv = 1.f / tot;
        #pragma unroll
        for (int k = 0; k < KK; ++k) sa[wv][k] = e[k] * inv;
    }
    __syncthreads();

    // ---- agg_b (one block-slice only) ----
    if (oty == 0 && kcz == 0) {
        int bl = tid >> 6, o = tid & 63;
        float s = 0.f;
        #pragma unroll
        for (int k = 0; k < KK; ++k) s += sa[bl][k] * bias[k * OO + o];
        agg_b[(b4 * 4 + bl) * OO + o] = s;
    }

    // ---- 3. fragment emit: thread = (lane6, j2); 9 j9 x 4 samples ----
    const int lane6 = tid >> 2;
    const int j2    = tid & 3;
    const int m     = lane6 & 31;
    const int kh2   = lane6 >> 5;
    const int cl    = kh2 * 8 + j2 * 2;          // local c in [0,16)
    #pragma unroll
    for (int bl = 0; bl < 4; ++bl) {
        const int b = b4 * 4 + bl;
        const float a0 = sa[bl][0], a1 = sa[bl][1], a2 = sa[bl][2], a3 = sa[bl][3];
        #pragma unroll
        for (int j9 = 0; j9 < 9; ++j9) {
            float s0, s1;
            {
                const float* p0 = swf + (0 * 32 + m) * 148 + cl * 9 + j9;
                const float* p1 = swf + (1 * 32 + m) * 148 + cl * 9 + j9;
                const float* p2 = swf + (2 * 32 + m) * 148 + cl * 9 + j9;
                const float* p3 = swf + (3 * 32 + m) * 148 + cl * 9 + j9;
                s0 = a0 * p0[0] + a1 * p1[0] + a2 * p2[0] + a3 * p3[0];
                s1 = a0 * p0[9] + a1 * p1[9] + a2 * p2[9] + a3 * p3[9];
            }
            wbf[(((size_t)b * 9 + j9) * 8 + oty * 4 + kcz) * 256 + tid] =
                (unsigned int)f2bf(s0) | ((unsigned int)f2bf(s1) << 16);
        }
    }
}

// ---------------- Kernel 3c: fused transpose + pool, vectorized ----------------
// xbf layout: [b][y][x][c] bf16 unpadded, c-block XOR-swizzled: word cp at cp ^ (((x+1)&7)<<2)
__global__ __launch_bounds__(256) void xpose_pool_kernel(const float* __restrict__ x,
                                                         unsigned int* __restrict__ xbf32,
                                                         float* __restrict__ pooled) {
    __shared__ float t2[64][68];        // [x_local][c] (+4 pad)
    __shared__ float s_red[4][64];
    const int y  = blockIdx.x;          // 0..127
    const int b  = blockIdx.y;          // 0..31
    const int x0 = blockIdx.z * 64;     // 0 or 64
    const int tid = threadIdx.x;
    // load: float4 along x, 4 c's per thread -> 4 instrs/thread, 1 KiB/wave-instr
    {
        const int xq = tid & 15;
        const int cb = (tid >> 4) * 4;
        #pragma unroll
        for (int i = 0; i < 4; ++i) {
            const int c = cb + i;
            const float4 v = *(const float4*)(x + (size_t)(b * CC + c) * HW
                                                + (size_t)y * WW + x0 + xq * 4);
            t2[xq * 4 + 0][c] = v.x;
            t2[xq * 4 + 1][c] = v.y;
            t2[xq * 4 + 2][c] = v.z;
            t2[xq * 4 + 3][c] = v.w;
        }
    }
    __syncthreads();
    // pool partials
    {
        const int c = tid & 63, q = tid >> 6;
        float s = 0.f;
        #pragma unroll
        for (int i = 0; i < 16; ++i) s += t2[q * 16 + i][c];
        s_red[q][c] = s;
    }
    // store: uint4 (8 bf16) per instr, 2 per thread, XOR group swizzle
    {
        const int xl  = tid >> 2;               // 0..63
        const int xg  = x0 + xl;
        const int key = (xg + 1) & 7;
        unsigned int* dst = xbf32 + ((size_t)(b * HH + y) * WW + xg) * 32;
        #pragma unroll
        for (int gg = 0; gg < 2; ++gg) {
            const int g = (tid & 3) + gg * 4;   // word group 0..7
            const float* src = &t2[xl][g * 8];
            uint4 pk;
            pk.x = (unsigned int)f2bf(src[0]) | ((unsigned int)f2bf(src[1]) << 16);
            pk.y = (unsigned int)f2bf(src[2]) | ((unsigned int)f2bf(src[3]) << 16);
            pk.z = (unsigned int)f2bf(src[4]) | ((unsigned int)f2bf(src[5]) << 16);
            pk.w = (unsigned int)f2bf(src[6]) | ((unsigned int)f2bf(src[7]) << 16);
            *(uint4*)(dst + (g ^ key) * 4) = pk;
        }
    }
    __syncthreads();
    if (tid < CC) {
        float s = s_red[0][tid] + s_red[1][tid] + s_red[2][tid] + s_red[3][tid];
        atomicAdd(pooled + b * CC + tid, s * (1.f / (float)HW));
    }
}

// ---------------- Kernel 4: conv as implicit GEMM, LDS-staged B, 2 output rows/block ----
// grid (Y=64, b=32), block 256 = 4 waves; LDS = 4 rows x 130 pos x 128 B = 66,560 B -> 2 blk/CU.
// Block covers output rows y0=2Y, y0+1; stages 4 input rows (y0-1..y0+2).
// Per-output-row staging drops 48->33 KB; A-fragment L2 traffic halves; barriers halve.
#define LROW 16640              // 130*128 bytes per LDS row
__global__ __launch_bounds__(256, 2) void conv_mfma_kernel(const short* __restrict__ xbf,
                                                           const short* __restrict__ wbf,
                                                           const float* __restrict__ agg_b,
                                                           float* __restrict__ out) {
    __shared__ __attribute__((aligned(16))) char ldsbuf[4 * LROW];
    unsigned int* lds32 = (unsigned int*)ldsbuf;

    const int s    = blockIdx.x;                  // 0..63
    const int Y    = ((s & 7) << 3) | (s >> 3);   // XCD-L2 clustering (bijective on 64)
    const int y0   = Y * 2;                       // output rows y0, y0+1
    const int b    = blockIdx.y;
    const int tid  = threadIdx.x;
    const int lane = tid & 63;
    const int w    = tid >> 6;

    // ---- zero x pads: 4 rows x {p=0, p=129} x 32 words = 256 words (all threads) ----
    {
        int r = tid >> 6;
        int q = tid & 63;
        int word = (q < 32) ? (r * (LROW/4) + q)
                            : (r * (LROW/4) + 129 * 32 + (q - 32));
        lds32[word] = 0u;
    }
    // ---- stage 4 rows (iy = y0-1 .. y0+2): 64 calls of 1 KiB, 16 per wave ----
    {
        const short* growb = xbf + (size_t)b * HH * WW * CC;
        #pragma unroll
        for (int i = 0; i < 16; ++i) {
            int call = w * 16 + i;          // wave-uniform
            int r   = call >> 4;            // 0..3
            int seg = call & 15;            // 0..15
            int iy  = y0 - 1 + r;
            if (iy >= 0 && iy < HH) {
                const short* g = growb + (size_t)iy * (WW * CC) + seg * 512 + lane * 8;
                char* lp = ldsbuf + r * LROW + 128 + seg * 1024;
                __builtin_amdgcn_global_load_lds((gbl_void_t*)g, (lds_void_t*)lp, 16, 0, 0);
            }
        }
    }
    // ---- zero out-of-range rows (y edges) ----
    if (Y == 0)  for (int i = tid; i < 4096; i += 256) lds32[32 + i] = 0u;
    if (Y == 63) for (int i = tid; i < 4096; i += 256) lds32[3 * (LROW/4) + 32 + i] = 0u;
    __syncthreads();

    const int otile = w & 1;
    const int o0    = otile * 32;
    const int x0    = (w >> 1) * 64;
    const int m     = lane & 31;
    const int kh2   = lane >> 5;
    const int cbase = kh2 * 16;

    f32x16 acc00 = {0,0,0,0,0,0,0,0,0,0,0,0,0,0,0,0};
    f32x16 acc01 = {0,0,0,0,0,0,0,0,0,0,0,0,0,0,0,0};
    f32x16 acc10 = {0,0,0,0,0,0,0,0,0,0,0,0,0,0,0,0};
    f32x16 acc11 = {0,0,0,0,0,0,0,0,0,0,0,0,0,0,0,0};

    const char* ldsc = ldsbuf;
    #pragma unroll
    for (int j9 = 0; j9 < 9; ++j9) {
        const int kh = j9 / 3, kw = j9 % 3;
        const short* Aj = wbf + (((size_t)b * 9 + j9) * 2 + otile) * 2048 + lane * 8;
        const int p0  = x0 + m + kw;
        const int sw  = ((m + kw) & 7) << 4;
        #pragma unroll
        for (int kc = 0; kc < 4; ++kc) {
            bf16x8 a = *(const bf16x8*)(Aj + kc * 512);
            const int c_off = (cbase + kc * 32) ^ sw;
            const int base0 = kh * LROW + p0 * 128 + c_off;      // dy=0 row r=kh
            bf16x8 b00 = *(const bf16x8*)(ldsc + base0);
            bf16x8 b01 = *(const bf16x8*)(ldsc + base0 + 32 * 128);
            bf16x8 b10 = *(const bf16x8*)(ldsc + base0 + LROW);  // dy=1 row r=kh+1
            bf16x8 b11 = *(const bf16x8*)(ldsc + base0 + LROW + 32 * 128);
            acc00 = __builtin_amdgcn_mfma_f32_32x32x16_bf16(a, b00, acc00, 0, 0, 0);
            acc01 = __builtin_amdgcn_mfma_f32_32x32x16_bf16(a, b01, acc01, 0, 0, 0);
            acc10 = __builtin_amdgcn_mfma_f32_32x32x16_bf16(a, b10, acc10, 0, 0, 0);
            acc11 = __builtin_amdgcn_mfma_f32_32x32x16_bf16(a, b11, acc11, 0, 0, 0);
        }
    }

    // epilogue: C/D row = (r&3) + 8*(r>>2) + 4*kh2 ; col = m
    #pragma unroll
    for (int r = 0; r < 16; ++r) {
        int o = o0 + (r & 3) + 8 * (r >> 2) + 4 * kh2;
        float bias = agg_b[b * OO + o];
        size_t base = ((size_t)(b * OO + o) * HH + y0) * WW;
        out[base + x0 + m]           = acc00[r] + bias;
        out[base + x0 + 32 + m]      = acc01[r] + bias;
        out[base + WW + x0 + m]      = acc10[r] + bias;
        out[base + WW + x0 + 32 + m] = acc11[r] + bias;
    }
}

// ================= fallback fp32 path (if workspace too small) =================
__global__ __launch_bounds__(256) void aggw_kernel(const float* __restrict__ attn,
                                                   const float* __restrict__ weight,
                                                   float* __restrict__ agg_w) {
    int idx = blockIdx.x * 256 + threadIdx.x;
    const int total = BB * CC * OO * 9;
    if (idx >= total) return;
    int j  = idx % 9;
    int t  = idx / 9;
    int o  = t & 63;
    int t2 = t >> 6;
    int c  = t2 & 63;
    int b  = t2 >> 6;
    float s = 0.f;
    #pragma unroll
    for (int k = 0; k < KK; ++k)
        s += attn[b * KK + k] * weight[((k * OO + o) * CC + c) * 9 + j];
    agg_w[idx] = s;
}

__global__ __launch_bounds__(256) void conv_kernel(const float* __restrict__ x,
                                                   const float* __restrict__ agg_w,
                                                   const float* __restrict__ agg_b,
                                                   float* __restrict__ out) {
    __shared__ float s_in[2][18 * 20];
    const int tid = threadIdx.x;
    const int tx = tid & 15, ty = tid >> 4;
    const int b  = blockIdx.z;
    const int o0 = blockIdx.y * 8;
    const int sy = (blockIdx.x >> 3) * 16;
    const int sx = (blockIdx.x & 7) * 16;

    const float* __restrict__ xb = x + (size_t)b * CC * HW;
    const float* __restrict__ wb = agg_w + (size_t)b * CC * OO * 9;

    float acc[8];
    #pragma unroll
    for (int o = 0; o < 8; ++o) acc[o] = agg_b[b * OO + o0 + o];

    auto load_ch = [&](int c, float* dst) {
        for (int i = tid; i < 18 * 18; i += 256) {
            int r   = i / 18;
            int col = i - r * 18;
            int gy = sy + r - 1;
            int gx = sx + col - 1;
            float v = 0.f;
            if (gy >= 0 && gy < HH && gx >= 0 && gx < WW)
                v = xb[c * HW + gy * WW + gx];
            dst[r * 20 + col] = v;
        }
    };

    load_ch(0, s_in[0]);
    __syncthreads();

    for (int c = 0; c < CC; ++c) {
        const int buf = c & 1;
        if (c + 1 < CC) load_ch(c + 1, s_in[buf ^ 1]);
        float in[3][3];
        #pragma unroll
        for (int kh = 0; kh < 3; ++kh)
            #pragma unroll
            for (int kw = 0; kw < 3; ++kw)
                in[kh][kw] = s_in[buf][(ty + kh) * 20 + (tx + kw)];
        const float* __restrict__ wc = wb + (c * OO + o0) * 9;
        #pragma unroll
        for (int o = 0; o < 8; ++o)
            #pragma unroll
            for (int kh = 0; kh < 3; ++kh)
                #pragma unroll
                for (int kw = 0; kw < 3; ++kw)
                    acc[o] += in[kh][kw] * wc[o * 9 + kh * 3 + kw];
        __syncthreads();
    }

    const int oy = sy + ty, ox = sx + tx;
    #pragma unroll
    for (int o = 0; o < 8; ++o)
        out[((size_t)(b * OO + o0 + o) * HH + oy) * WW + ox] = acc[o];
}

extern "C" void kernel_launch(void* const* d_in, const int* in_sizes, int n_in,
                              void* d_out, int out_size, void* d_ws, size_t ws_size,
                              hipStream_t stream) {
    const float* x      = (const float*)d_in[0];
    const float* scale  = (const float*)d_in[1];
    const float* fc1_w  = (const float*)d_in[2];
    const float* fc2_w  = (const float*)d_in[3];
    const float* fc2_b  = (const float*)d_in[4];
    const float* weight = (const float*)d_in[5];
    const float* bias   = (const float*)d_in[6];
    float* out = (float*)d_out;

    // workspace layout (MFMA path):
    //   xbf : 32*128*128*64 bf16 = 67,108,864 B  (offset 0, pre-swizzled)
    //   wbf : 32*9*2*4*64*8 bf16 =  2,359,296 B  (fragment-contiguous)
    //   floats: pooled[2048] attn[128] agg_b[2048]
    const size_t XBF_BYTES = (size_t)BB * HH * WW * CC * 2;
    const size_t WBF_BYTES = (size_t)BB * 9 * OO * CC * 2;
    const size_t NEED = XBF_BYTES + WBF_BYTES + (2048 + 128 + 2048) * 4 + 256;

    if (ws_size >= NEED) {
        short*        xbf   = (short*)d_ws;
        unsigned int* xbf32 = (unsigned int*)d_ws;
        unsigned int* wbf32 = (unsigned int*)((char*)d_ws + XBF_BYTES);
        short*        wbf   = (short*)wbf32;
        float*        fls   = (float*)((char*)d_ws + XBF_BYTES + WBF_BYTES);
        float* pooled = fls;
        float* agg_b  = fls + 2048 + 128;

        zero_pool_kernel<<<8, 256, 0, stream>>>(pooled);
        xpose_pool_kernel<<<dim3(HH, BB, 2), 256, 0, stream>>>(x, xbf32, pooled);
        aggw_fused_kernel<<<dim3(8, 2, 4), 256, 0, stream>>>(pooled, fc1_w, fc2_w, fc2_b,
                                                             scale, bias, weight, agg_b, wbf32);
        conv_mfma_kernel<<<dim3(64, BB), 256, 0, stream>>>(xbf, wbf, agg_b, out);
    } else {
        float* ws     = (float*)d_ws;
        float* attn   = ws;
        float* agg_b  = ws + 128;
        float* pooled = ws + 128 + 2048;
        float* agg_w  = ws + 128 + 2048 + 2048;
        pool_kernel<<<BB * CC, 256, 0, stream>>>(x, pooled);
        attn_kernel<<<1, 256, 0, stream>>>(pooled, fc1_w, fc2_w, fc2_b, scale, bias, attn, agg_b);
        const int aggw_total = BB * CC * OO * 9;
        aggw_kernel<<<(aggw_total + 255) / 256, 256, 0, stream>>>(attn, weight, agg_w);
        conv_kernel<<<dim3(64, 8, BB), 256, 0, stream>>>(x, agg_w, agg_b, out);
    }
}

// Round 7
// 299.387 us; speedup vs baseline: 1.0196x; 1.0196x over previous
//
#include <hip/hip_runtime.h>
#include <hip/hip_bf16.h>

#define BB 32
#define CC 64
#define HH 128
#define WW 128
#define OO 64
#define KK 4
#define HIDDEN 17
#define HW (HH*WW)

typedef __attribute__((ext_vector_type(8)))  short bf16x8;
typedef __attribute__((ext_vector_type(16))) float f32x16;

typedef __attribute__((address_space(3))) void       lds_void_t;
typedef const __attribute__((address_space(1))) void gbl_void_t;

__device__ __forceinline__ unsigned short f2bf(float f) {
    unsigned u = __float_as_uint(f);
    unsigned r = (u + 0x7FFFu + ((u >> 16) & 1u)) >> 16;   // RNE
    return (unsigned short)r;
}

// ---------------- zero pooled (must precede xpose_pool's atomics) ----------------
__global__ __launch_bounds__(256) void zero_pool_kernel(float* __restrict__ pooled) {
    int i = blockIdx.x * 256 + threadIdx.x;
    if (i < BB * CC) pooled[i] = 0.f;
}

// ---------------- Kernel 1 (fallback only): adaptive avg pool to [B,C] ----------------
__global__ __launch_bounds__(256) void pool_kernel(const float* __restrict__ x,
                                                   float* __restrict__ pooled) {
    int bc = blockIdx.x;              // b*64 + c
    const float* p = x + (size_t)bc * HW;
    float s = 0.f;
    for (int i = threadIdx.x; i < HW; i += 256) s += p[i];
    #pragma unroll
    for (int off = 32; off > 0; off >>= 1) s += __shfl_down(s, off, 64);
    __shared__ float warp_s[4];
    int lane = threadIdx.x & 63, wv = threadIdx.x >> 6;
    if (lane == 0) warp_s[wv] = s;
    __syncthreads();
    if (threadIdx.x == 0) {
        float t = warp_s[0] + warp_s[1] + warp_s[2] + warp_s[3];
        pooled[bc] = t * (1.f / (float)HW);
    }
}

// ---------------- Kernel 2 (fallback only): MLP -> softmax -> attn, agg_b ----------------
__global__ __launch_bounds__(256) void attn_kernel(const float* __restrict__ pooled,
                                                   const float* __restrict__ fc1_w,
                                                   const float* __restrict__ fc2_w,
                                                   const float* __restrict__ fc2_b,
                                                   const float* __restrict__ scale,
                                                   const float* __restrict__ bias,
                                                   float* __restrict__ attn,
                                                   float* __restrict__ agg_b) {
    __shared__ float s_attn[BB * KK];
    int tid = threadIdx.x;
    if (tid < BB) {
        int b = tid;
        const float* pb = pooled + b * CC;
        float h[HIDDEN];
        #pragma unroll
        for (int i = 0; i < HIDDEN; ++i) {
            float s = 0.f;
            for (int c = 0; c < CC; ++c) s += pb[c] * fc1_w[i * CC + c];
            h[i] = fmaxf(s, 0.f);
        }
        float sc = scale[0];
        float logits[KK];
        #pragma unroll
        for (int k = 0; k < KK; ++k) {
            float s = fc2_b[k];
            for (int j = 0; j < HIDDEN; ++j) s += h[j] * fc2_w[k * (HIDDEN + 2) + j];
            s += sc * fc2_w[k * (HIDDEN + 2) + HIDDEN];
            s += sc * fc2_w[k * (HIDDEN + 2) + HIDDEN + 1];
            logits[k] = s;
        }
        float m = fmaxf(fmaxf(logits[0], logits[1]), fmaxf(logits[2], logits[3]));
        float e[KK], tot = 0.f;
        #pragma unroll
        for (int k = 0; k < KK; ++k) { e[k] = __expf(logits[k] - m); tot += e[k]; }
        float inv = 1.f / tot;
        #pragma unroll
        for (int k = 0; k < KK; ++k) {
            float a = e[k] * inv;
            s_attn[b * KK + k] = a;
            attn[b * KK + k] = a;
        }
    }
    __syncthreads();
    for (int i = tid; i < BB * OO; i += blockDim.x) {
        int b = i >> 6;
        int o = i & 63;
        float s = 0.f;
        #pragma unroll
        for (int k = 0; k < KK; ++k) s += s_attn[b * KK + k] * bias[k * OO + o];
        agg_b[i] = s;
    }
}

// ---------------- Kernel 3a: fused MLP + weight-mix -> bf16 fragment layout ----------------
// grid (b4=8, otile=2, kc=4), 256 thr. (verified round 5 — unchanged)
// wbf layout: [b][j9][otile(2)][kc(4)][lane(64)][j2(4)] u32
__global__ __launch_bounds__(256) void aggw_fused_kernel(const float* __restrict__ pooled,
                                                         const float* __restrict__ fc1_w,
                                                         const float* __restrict__ fc2_w,
                                                         const float* __restrict__ fc2_b,
                                                         const float* __restrict__ scale,
                                                         const float* __restrict__ bias,
                                                         const float* __restrict__ weight,
                                                         float* __restrict__ agg_b,
                                                         unsigned int* __restrict__ wbf) {
    __shared__ float4 sw4[128 * 37];     // 128 segs x (36 data + 1 pad) float4 = 75,776 B
    __shared__ float  sh[4][20];         // per-sample hidden
    __shared__ float  sa[4][4];          // per-sample attention
    const float* swf = (const float*)sw4;

    const int tid = threadIdx.x;
    const int b4  = blockIdx.x;          // 0..7
    const int oty = blockIdx.y;          // otile 0..1
    const int kcz = blockIdx.z;          // kc 0..3

    // ---- 1. stage weight slice: 4608 float4, 18 per thread, coalesced ----
    {
        const float4* w4 = (const float4*)weight;
        #pragma unroll
        for (int it = 0; it < 18; ++it) {
            int i   = tid + it * 256;
            int seg = i / 36;            // k*32 + o_local
            int off = i - seg * 36;
            int k   = seg >> 5;
            int o   = seg & 31;
            sw4[seg * 37 + off] = w4[(size_t)(k * 64 + oty * 32 + o) * 144 + kcz * 36 + off];
        }
    }
    // ---- 2. MLP for 4 samples (wave wv handles sample b4*4+wv) ----
    const int wv = tid >> 6, lane = tid & 63;
    const int bb = b4 * 4 + wv;
    if (lane < HIDDEN) {
        const float* pb = pooled + bb * CC;
        const float* f1 = fc1_w + lane * CC;
        float s = 0.f;
        #pragma unroll
        for (int c = 0; c < CC; ++c) s += pb[c] * f1[c];
        sh[wv][lane] = fmaxf(s, 0.f);
    }
    __syncthreads();
    if (lane == 0) {
        float sc = scale[0];
        float lg[KK];
        #pragma unroll
        for (int k = 0; k < KK; ++k) {
            float s = fc2_b[k];
            #pragma unroll
            for (int j = 0; j < HIDDEN; ++j) s += sh[wv][j] * fc2_w[k * (HIDDEN + 2) + j];
            s += sc * fc2_w[k * (HIDDEN + 2) + HIDDEN];
            s += sc * fc2_w[k * (HIDDEN + 2) + HIDDEN + 1];
            lg[k] = s;
        }
        float m = fmaxf(fmaxf(lg[0], lg[1]), fmaxf(lg[2], lg[3]));
        float e[KK], tot = 0.f;
        #pragma unroll
        for (int k = 0; k < KK; ++k) { e[k] = __expf(lg[k] - m); tot += e[k]; }
        float inv = 1.f / tot;
        #pragma unroll
        for (int k = 0; k < KK; ++k) sa[wv][k] = e[k] * inv;
    }
    __syncthreads();

    // ---- agg_b (one block-slice only) ----
    if (oty == 0 && kcz == 0) {
        int bl = tid >> 6, o = tid & 63;
        float s = 0.f;
        #pragma unroll
        for (int k = 0; k < KK; ++k) s += sa[bl][k] * bias[k * OO + o];
        agg_b[(b4 * 4 + bl) * OO + o] = s;
    }

    // ---- 3. fragment emit: thread = (lane6, j2); 9 j9 x 4 samples ----
    const int lane6 = tid >> 2;
    const int j2    = tid & 3;
    const int m     = lane6 & 31;
    const int kh2   = lane6 >> 5;
    const int cl    = kh2 * 8 + j2 * 2;          // local c in [0,16)
    #pragma unroll
    for (int bl = 0; bl < 4; ++bl) {
        const int b = b4 * 4 + bl;
        const float a0 = sa[bl][0], a1 = sa[bl][1], a2 = sa[bl][2], a3 = sa[bl][3];
        #pragma unroll
        for (int j9 = 0; j9 < 9; ++j9) {
            float s0, s1;
            {
                const float* p0 = swf + (0 * 32 + m) * 148 + cl * 9 + j9;
                const float* p1 = swf + (1 * 32 + m) * 148 + cl * 9 + j9;
                const float* p2 = swf + (2 * 32 + m) * 148 + cl * 9 + j9;
                const float* p3 = swf + (3 * 32 + m) * 148 + cl * 9 + j9;
                s0 = a0 * p0[0] + a1 * p1[0] + a2 * p2[0] + a3 * p3[0];
                s1 = a0 * p0[9] + a1 * p1[9] + a2 * p2[9] + a3 * p3[9];
            }
            wbf[(((size_t)b * 9 + j9) * 8 + oty * 4 + kcz) * 256 + tid] =
                (unsigned int)f2bf(s0) | ((unsigned int)f2bf(s1) << 16);
        }
    }
}

// ---------------- Kernel 3c: fused transpose + pool, vectorized (verified round 5) ----------------
// xbf layout: [b][y][x][c] bf16 unpadded, c-block XOR-swizzled: word cp at cp ^ (((x+1)&7)<<2)
__global__ __launch_bounds__(256) void xpose_pool_kernel(const float* __restrict__ x,
                                                         unsigned int* __restrict__ xbf32,
                                                         float* __restrict__ pooled) {
    __shared__ float t2[64][68];        // [x_local][c] (+4 pad)
    __shared__ float s_red[4][64];
    const int y  = blockIdx.x;          // 0..127
    const int b  = blockIdx.y;          // 0..31
    const int x0 = blockIdx.z * 64;     // 0 or 64
    const int tid = threadIdx.x;
    {
        const int xq = tid & 15;
        const int cb = (tid >> 4) * 4;
        #pragma unroll
        for (int i = 0; i < 4; ++i) {
            const int c = cb + i;
            const float4 v = *(const float4*)(x + (size_t)(b * CC + c) * HW
                                                + (size_t)y * WW + x0 + xq * 4);
            t2[xq * 4 + 0][c] = v.x;
            t2[xq * 4 + 1][c] = v.y;
            t2[xq * 4 + 2][c] = v.z;
            t2[xq * 4 + 3][c] = v.w;
        }
    }
    __syncthreads();
    {
        const int c = tid & 63, q = tid >> 6;
        float s = 0.f;
        #pragma unroll
        for (int i = 0; i < 16; ++i) s += t2[q * 16 + i][c];
        s_red[q][c] = s;
    }
    {
        const int xl  = tid >> 2;               // 0..63
        const int xg  = x0 + xl;
        const int key = (xg + 1) & 7;
        unsigned int* dst = xbf32 + ((size_t)(b * HH + y) * WW + xg) * 32;
        #pragma unroll
        for (int gg = 0; gg < 2; ++gg) {
            const int g = (tid & 3) + gg * 4;   // word group 0..7
            const float* src = &t2[xl][g * 8];
            uint4 pk;
            pk.x = (unsigned int)f2bf(src[0]) | ((unsigned int)f2bf(src[1]) << 16);
            pk.y = (unsigned int)f2bf(src[2]) | ((unsigned int)f2bf(src[3]) << 16);
            pk.z = (unsigned int)f2bf(src[4]) | ((unsigned int)f2bf(src[5]) << 16);
            pk.w = (unsigned int)f2bf(src[6]) | ((unsigned int)f2bf(src[7]) << 16);
            *(uint4*)(dst + (g ^ key) * 4) = pk;
        }
    }
    __syncthreads();
    if (tid < CC) {
        float s = s_red[0][tid] + s_red[1][tid] + s_red[2][tid] + s_red[3][tid];
        atomicAdd(pooled + b * CC + tid, s * (1.f / (float)HW));
    }
}

// ---------------- Kernel 4: persistent rolling-window conv (T3/T4 counted-vmcnt) ----------
// grid (Ycl=16, b=32) = 512 blocks, 256 thr, 4-slot LDS ring (66,560 B -> 2 blk/CU).
// Block walks NY=8 output rows; 1 new input row (16.6 KB) staged per row, in flight
// DURING the previous row's MFMAs (vmcnt(4), never 0 mid-loop). A-fragments + bias live
// in registers for the whole block -> compute phase is vmem-wait-free.
#define LROW 16640              // 130*128 bytes per LDS slot
#define NY 8
__global__ __launch_bounds__(256, 2) void conv_mfma_kernel(const short* __restrict__ xbf,
                                                           const short* __restrict__ wbf,
                                                           const float* __restrict__ agg_b,
                                                           float* __restrict__ out) {
    __shared__ __attribute__((aligned(16))) char ldsbuf[4 * LROW];
    unsigned int* lds32 = (unsigned int*)ldsbuf;

    const int Ycl  = blockIdx.x;          // 0..15
    const int y0   = Ycl * NY;
    const int b    = blockIdx.y;
    const int tid  = threadIdx.x;
    const int lane = tid & 63;
    const int w    = tid >> 6;

    // ---- zero x pads p=0 / p=129 for all 4 slots (never touched by staging) ----
    {
        int r = tid >> 6;                 // slot
        int q = tid & 63;
        int word = (q < 32) ? (r * (LROW / 4) + q)
                            : (r * (LROW / 4) + 129 * 32 + (q - 32));
        lds32[word] = 0u;
    }

    const short* growb = xbf + (size_t)b * HH * WW * CC;

    auto stage4 = [&](int row, int slot) {      // 4 x 1KiB gload_lds per wave
        const short* g = growb + (size_t)row * (WW * CC);
        #pragma unroll
        for (int i = 0; i < 4; ++i) {
            int seg = w * 4 + i;                // wave-uniform
            const short* gp = g + seg * 512 + lane * 8;
            char* lp = ldsbuf + slot * LROW + 128 + seg * 1024;
            __builtin_amdgcn_global_load_lds((gbl_void_t*)gp, (lds_void_t*)lp, 16, 0, 0);
        }
    };
    auto zero_slot = [&](int slot) {            // 16 KiB of zeros via ds_write_b128
        uint4* p = (uint4*)(ldsbuf + slot * LROW + 128);
        #pragma unroll
        for (int i = 0; i < 4; ++i) p[tid + i * 256] = make_uint4(0u, 0u, 0u, 0u);
    };

    // ---- prologue: slots 0..2 = input rows y0-1, y0, y0+1 ----
    if (y0 - 1 >= 0) stage4(y0 - 1, 0); else zero_slot(0);
    stage4(y0,     1);
    stage4(y0 + 1, 2);                    // y0+1 <= 121 always valid
    __syncthreads();                      // full drain (prologue only)

    // ---- per-wave geometry ----
    const int otile = w & 1;
    const int o0    = otile * 32;
    const int x0    = (w >> 1) * 64;
    const int m     = lane & 31;
    const int kh2   = lane >> 5;
    const int cbase = kh2 * 16;

    // ---- A fragments in registers for the whole block (36 x bf16x8) ----
    bf16x8 A[9][4];
    #pragma unroll
    for (int j9 = 0; j9 < 9; ++j9) {
        const short* Aj = wbf + (((size_t)b * 9 + j9) * 2 + otile) * 2048 + lane * 8;
        #pragma unroll
        for (int kc = 0; kc < 4; ++kc) A[j9][kc] = *(const bf16x8*)(Aj + kc * 512);
    }
    // ---- bias preload (acc init; keeps epilogue vmem-free of loads) ----
    float biasv[16];
    #pragma unroll
    for (int r = 0; r < 16; ++r)
        biasv[r] = agg_b[b * OO + o0 + (r & 3) + 8 * (r >> 2) + 4 * kh2];

    for (int iy = 0; iy < NY; ++iy) {
        // barrier1: all waves done READING the slot we are about to recycle
        asm volatile("s_waitcnt lgkmcnt(0)" ::: "memory");
        __builtin_amdgcn_s_barrier();
        // issue next row (t_rel = iy+3) into recycled slot
        bool did = false;
        if (iy < NY - 1) {
            const int row = y0 + iy + 2;            // = (y0-1) + (iy+3)
            const int slot = (iy + 3) & 3;
            if (row < HH) { stage4(row, slot); did = true; }
            else          zero_slot(slot);
        }
        // counted wait: previous iteration's 4 loads done; this iteration's may fly
        if (did) asm volatile("s_waitcnt vmcnt(4) lgkmcnt(0)" ::: "memory");
        else     asm volatile("s_waitcnt vmcnt(0) lgkmcnt(0)" ::: "memory");
        __builtin_amdgcn_s_barrier();               // barrier2: slots iy..iy+2 valid
        __builtin_amdgcn_sched_barrier(0);

        f32x16 acc0, acc1;
        #pragma unroll
        for (int r = 0; r < 16; ++r) { acc0[r] = biasv[r]; acc1[r] = biasv[r]; }

        #pragma unroll
        for (int j9 = 0; j9 < 9; ++j9) {
            const int kh = j9 / 3, kw = j9 % 3;
            const int slot = (iy + kh) & 3;
            const int p0 = x0 + m + kw;
            const int sw = ((m + kw) & 7) << 4;
            const int base0 = slot * LROW + p0 * 128;
            #pragma unroll
            for (int kc = 0; kc < 4; ++kc) {
                const int c_off = (cbase + kc * 32) ^ sw;
                bf16x8 b0 = *(const bf16x8*)(ldsbuf + base0 + c_off);
                bf16x8 b1 = *(const bf16x8*)(ldsbuf + base0 + 32 * 128 + c_off);
                acc0 = __builtin_amdgcn_mfma_f32_32x32x16_bf16(A[j9][kc], b0, acc0, 0, 0, 0);
                acc1 = __builtin_amdgcn_mfma_f32_32x32x16_bf16(A[j9][kc], b1, acc1, 0, 0, 0);
            }
        }

        const int y = y0 + iy;
        #pragma unroll
        for (int r = 0; r < 16; ++r) {
            int o = o0 + (r & 3) + 8 * (r >> 2) + 4 * kh2;
            size_t base = ((size_t)(b * OO + o) * HH + y) * WW;
            out[base + x0 + m]      = acc0[r];
            out[base + x0 + 32 + m] = acc1[r];
        }
    }
}

// ================= fallback fp32 path (if workspace too small) =================
__global__ __launch_bounds__(256) void aggw_kernel(const float* __restrict__ attn,
                                                   const float* __restrict__ weight,
                                                   float* __restrict__ agg_w) {
    int idx = blockIdx.x * 256 + threadIdx.x;
    const int total = BB * CC * OO * 9;
    if (idx >= total) return;
    int j  = idx % 9;
    int t  = idx / 9;
    int o  = t & 63;
    int t2 = t >> 6;
    int c  = t2 & 63;
    int b  = t2 >> 6;
    float s = 0.f;
    #pragma unroll
    for (int k = 0; k < KK; ++k)
        s += attn[b * KK + k] * weight[((k * OO + o) * CC + c) * 9 + j];
    agg_w[idx] = s;
}

__global__ __launch_bounds__(256) void conv_kernel(const float* __restrict__ x,
                                                   const float* __restrict__ agg_w,
                                                   const float* __restrict__ agg_b,
                                                   float* __restrict__ out) {
    __shared__ float s_in[2][18 * 20];
    const int tid = threadIdx.x;
    const int tx = tid & 15, ty = tid >> 4;
    const int b  = blockIdx.z;
    const int o0 = blockIdx.y * 8;
    const int sy = (blockIdx.x >> 3) * 16;
    const int sx = (blockIdx.x & 7) * 16;

    const float* __restrict__ xb = x + (size_t)b * CC * HW;
    const float* __restrict__ wb = agg_w + (size_t)b * CC * OO * 9;

    float acc[8];
    #pragma unroll
    for (int o = 0; o < 8; ++o) acc[o] = agg_b[b * OO + o0 + o];

    auto load_ch = [&](int c, float* dst) {
        for (int i = tid; i < 18 * 18; i += 256) {
            int r   = i / 18;
            int col = i - r * 18;
            int gy = sy + r - 1;
            int gx = sx + col - 1;
            float v = 0.f;
            if (gy >= 0 && gy < HH && gx >= 0 && gx < WW)
                v = xb[c * HW + gy * WW + gx];
            dst[r * 20 + col] = v;
        }
    };

    load_ch(0, s_in[0]);
    __syncthreads();

    for (int c = 0; c < CC; ++c) {
        const int buf = c & 1;
        if (c + 1 < CC) load_ch(c + 1, s_in[buf ^ 1]);
        float in[3][3];
        #pragma unroll
        for (int kh = 0; kh < 3; ++kh)
            #pragma unroll
            for (int kw = 0; kw < 3; ++kw)
                in[kh][kw] = s_in[buf][(ty + kh) * 20 + (tx + kw)];
        const float* __restrict__ wc = wb + (c * OO + o0) * 9;
        #pragma unroll
        for (int o = 0; o < 8; ++o)
            #pragma unroll
            for (int kh = 0; kh < 3; ++kh)
                #pragma unroll
                for (int kw = 0; kw < 3; ++kw)
                    acc[o] += in[kh][kw] * wc[o * 9 + kh * 3 + kw];
        __syncthreads();
    }

    const int oy = sy + ty, ox = sx + tx;
    #pragma unroll
    for (int o = 0; o < 8; ++o)
        out[((size_t)(b * OO + o0 + o) * HH + oy) * WW + ox] = acc[o];
}

extern "C" void kernel_launch(void* const* d_in, const int* in_sizes, int n_in,
                              void* d_out, int out_size, void* d_ws, size_t ws_size,
                              hipStream_t stream) {
    const float* x      = (const float*)d_in[0];
    const float* scale  = (const float*)d_in[1];
    const float* fc1_w  = (const float*)d_in[2];
    const float* fc2_w  = (const float*)d_in[3];
    const float* fc2_b  = (const float*)d_in[4];
    const float* weight = (const float*)d_in[5];
    const float* bias   = (const float*)d_in[6];
    float* out = (float*)d_out;

    // workspace layout (MFMA path):
    //   xbf : 32*128*128*64 bf16 = 67,108,864 B  (offset 0, pre-swizzled)
    //   wbf : 32*9*2*4*64*8 bf16 =  2,359,296 B  (fragment-contiguous)
    //   floats: pooled[2048] attn[128] agg_b[2048]
    const size_t XBF_BYTES = (size_t)BB * HH * WW * CC * 2;
    const size_t WBF_BYTES = (size_t)BB * 9 * OO * CC * 2;
    const size_t NEED = XBF_BYTES + WBF_BYTES + (2048 + 128 + 2048) * 4 + 256;

    if (ws_size >= NEED) {
        short*        xbf   = (short*)d_ws;
        unsigned int* xbf32 = (unsigned int*)d_ws;
        unsigned int* wbf32 = (unsigned int*)((char*)d_ws + XBF_BYTES);
        short*        wbf   = (short*)wbf32;
        float*        fls   = (float*)((char*)d_ws + XBF_BYTES + WBF_BYTES);
        float* pooled = fls;
        float* agg_b  = fls + 2048 + 128;

        zero_pool_kernel<<<8, 256, 0, stream>>>(pooled);
        xpose_pool_kernel<<<dim3(HH, BB, 2), 256, 0, stream>>>(x, xbf32, pooled);
        aggw_fused_kernel<<<dim3(8, 2, 4), 256, 0, stream>>>(pooled, fc1_w, fc2_w, fc2_b,
                                                             scale, bias, weight, agg_b, wbf32);
        conv_mfma_kernel<<<dim3(16, BB), 256, 0, stream>>>(xbf, wbf, agg_b, out);
    } else {
        float* ws     = (float*)d_ws;
        float* attn   = ws;
        float* agg_b  = ws + 128;
        float* pooled = ws + 128 + 2048;
        float* agg_w  = ws + 128 + 2048 + 2048;
        pool_kernel<<<BB * CC, 256, 0, stream>>>(x, pooled);
        attn_kernel<<<1, 256, 0, stream>>>(pooled, fc1_w, fc2_w, fc2_b, scale, bias, attn, agg_b);
        const int aggw_total = BB * CC * OO * 9;
        aggw_kernel<<<(aggw_total + 255) / 256, 256, 0, stream>>>(attn, weight, agg_w);
        conv_kernel<<<dim3(64, 8, BB), 256, 0, stream>>>(x, agg_w, agg_b, out);
    }
}